// Round 2
// baseline (76.820 us; speedup 1.0000x reference)
//
#include <hip/hip_runtime.h>

// MVDR: per (b,t,f) cell, invert 5x5 complex Phi_N in registers (in-place
// Gauss-Jordan, partial pivoting via unrolled predicated row swaps + reverse
// column fixup), then STREAM Phi_S to accumulate trace(N^-1 S) and
// a1 = N^-1 S[:,0] — halves live register state vs augmented [N|S] GJ,
// eliminating the scratch spill seen in round 1 (WRITE_SIZE 25MB vs 4.9MB).

constexpr int MD = 5;
constexpr int BB = 2, TT = 600, FF = 513;
constexpr int TOTAL = BB * TT * FF;

__global__ __launch_bounds__(256, 3) void mvdr_kernel(
    const float* __restrict__ spec,    // (B,T,F,M,2)
    const float* __restrict__ corrS,   // (B,T,F,M,M,2)
    const float* __restrict__ corrN,   // (B,T,F,M,M,2)
    float* __restrict__ out)           // (B,F,T,2)
{
    int idx = blockIdx.x * blockDim.x + threadIdx.x;
    if (idx >= TOTAL) return;
    int f  = idx % FF;
    int bt = idx / FF;
    int t  = bt % TT;
    int b  = bt / TT;

    float Ar[MD][MD], Ai[MD][MD];
    const float2* __restrict__ pn = reinterpret_cast<const float2*>(corrN) + (size_t)idx * (MD * MD);
#pragma unroll
    for (int i = 0; i < MD; ++i)
#pragma unroll
        for (int j = 0; j < MD; ++j) {
            float2 v = pn[i * MD + j];
            Ar[i][j] = v.x; Ai[i][j] = v.y;
        }
#pragma unroll
    for (int i = 0; i < MD; ++i) { Ar[i][i] += 1e-7f; Ai[i][i] += 1e-7f; }

    // ---- in-place Gauss-Jordan inversion with partial pivoting ----
    bool sw[MD][MD];
#pragma unroll
    for (int k = 0; k < MD; ++k) {
        // bubble the max-|pivot| row up via predicated swaps
#pragma unroll
        for (int j = k + 1; j < MD; ++j) {
            bool s = (Ar[j][k] * Ar[j][k] + Ai[j][k] * Ai[j][k]) >
                     (Ar[k][k] * Ar[k][k] + Ai[k][k] * Ai[k][k]);
            sw[k][j] = s;
#pragma unroll
            for (int c = 0; c < MD; ++c) {
                float ta, tb;
                ta = Ar[k][c]; tb = Ar[j][c];
                Ar[k][c] = s ? tb : ta; Ar[j][c] = s ? ta : tb;
                ta = Ai[k][c]; tb = Ai[j][c];
                Ai[k][c] = s ? tb : ta; Ai[j][c] = s ? ta : tb;
            }
        }
        float pr = Ar[k][k], pi = Ai[k][k];
        float invd = 1.0f / (pr * pr + pi * pi);
        float ipr = pr * invd, ipi = -pi * invd;   // 1/pivot
        Ar[k][k] = ipr; Ai[k][k] = ipi;
#pragma unroll
        for (int c = 0; c < MD; ++c) {
            if (c == k) continue;
            float xr = Ar[k][c], xi = Ai[k][c];
            Ar[k][c] = xr * ipr - xi * ipi;
            Ai[k][c] = xr * ipi + xi * ipr;
        }
#pragma unroll
        for (int i2 = 0; i2 < MD; ++i2) {
            if (i2 == k) continue;
            float fr = Ar[i2][k], fi = Ai[i2][k];
#pragma unroll
            for (int c = 0; c < MD; ++c) {
                if (c == k) continue;
                float xr = Ar[k][c], xi = Ai[k][c];
                Ar[i2][c] -= fr * xr - fi * xi;
                Ai[i2][c] -= fr * xi + fi * xr;
            }
            Ar[i2][k] = -(fr * ipr - fi * ipi);
            Ai[i2][k] = -(fr * ipi + fi * ipr);
        }
    }
    // reverse-order column fixup for the row interchanges
#pragma unroll
    for (int k = MD - 1; k >= 0; --k) {
#pragma unroll
        for (int j = MD - 1; j > k; --j) {
            bool s = sw[k][j];
#pragma unroll
            for (int r = 0; r < MD; ++r) {
                float ta, tb;
                ta = Ar[r][k]; tb = Ar[r][j];
                Ar[r][k] = s ? tb : ta; Ar[r][j] = s ? ta : tb;
                ta = Ai[r][k]; tb = Ai[r][j];
                Ai[r][k] = s ? tb : ta; Ai[r][j] = s ? ta : tb;
            }
        }
    }

    // ---- stream Phi_S: trace(N^-1 S) and a1 = N^-1 S[:,0] ----
    const float2* __restrict__ ps = reinterpret_cast<const float2*>(corrS) + (size_t)idx * (MD * MD);
    float trr = 0.f, tri = 0.f;
    float a1r[MD] = {0.f, 0.f, 0.f, 0.f, 0.f};
    float a1i[MD] = {0.f, 0.f, 0.f, 0.f, 0.f};
#pragma unroll
    for (int j = 0; j < MD; ++j) {          // row of S (memory-sequential)
#pragma unroll
        for (int i = 0; i < MD; ++i) {      // col of S
            float2 sv = ps[j * MD + i];
            // trace += inv[i][j] * S[j][i]
            trr += Ar[i][j] * sv.x - Ai[i][j] * sv.y;
            tri += Ar[i][j] * sv.y + Ai[i][j] * sv.x;
            if (i == 0) {
#pragma unroll
                for (int m = 0; m < MD; ++m) {
                    a1r[m] += Ar[m][j] * sv.x - Ai[m][j] * sv.y;
                    a1i[m] += Ar[m][j] * sv.y + Ai[m][j] * sv.x;
                }
            }
        }
    }
    const float eps = 1.1920929e-07f;
    trr += eps; tri += eps;

    // z = sum_m conj(a1[m]) * x[m]
    const float2* __restrict__ px = reinterpret_cast<const float2*>(spec) + (size_t)idx * MD;
    float zr = 0.f, zi = 0.f;
#pragma unroll
    for (int m = 0; m < MD; ++m) {
        float2 x = px[m];
        zr += a1r[m] * x.x + a1i[m] * x.y;
        zi += a1r[m] * x.y - a1i[m] * x.x;
    }

    // S_hat = z / conj(trace + eps(1+i)) = z * (trr + i*tri) / |d|^2
    float inv2 = 1.0f / (trr * trr + tri * tri);
    float shr = (zr * trr - zi * tri) * inv2;
    float shi = (zr * tri + zi * trr) * inv2;

    float2* __restrict__ po = reinterpret_cast<float2*>(out);
    po[((size_t)b * FF + f) * TT + t] = make_float2(shr, shi);
}

extern "C" void kernel_launch(void* const* d_in, const int* in_sizes, int n_in,
                              void* d_out, int out_size, void* d_ws, size_t ws_size,
                              hipStream_t stream) {
    const float* spec  = (const float*)d_in[0];
    const float* corrS = (const float*)d_in[1];
    const float* corrN = (const float*)d_in[2];
    float* out = (float*)d_out;

    int blocks = (TOTAL + 255) / 256;
    mvdr_kernel<<<blocks, 256, 0, stream>>>(spec, corrS, corrN, out);
}

// Round 3
// 55.410 us; speedup vs baseline: 1.3864x; 1.3864x over previous
//
#include <hip/hip_runtime.h>

// MVDR: per (b,t,f) cell solve with 5x5 complex inversion.
// Round-3 change: inputs staged via global_load_lds (width 16) — round 1/2
// were VMEM-transaction-bound (per-lane stride 200B -> 64 transactions per
// load instr, ~34M total). Coalesced 1KB/wave staging cuts that ~8x.
// Two-phase LDS reuse: N -> invert (while S stages async) -> stream S.

constexpr int MD = 5;
constexpr int BB = 2, TT = 600, FF = 513;
constexpr int TOTAL = BB * TT * FF;
constexpr int CELLS = 128;                 // cells per block
constexpr int MATB  = CELLS * 200;         // 25600 B per corr buffer chunk
constexpr int SPECB = CELLS * 40;          // 5120 B spec chunk

typedef const __attribute__((address_space(1))) void* gas_t;
typedef __attribute__((address_space(3))) void* las_t;

__device__ __forceinline__ void load_lds16(const void* g, void* l) {
    __builtin_amdgcn_global_load_lds((gas_t)g, (las_t)l, 16, 0, 0);
}

__global__ __launch_bounds__(128, 2) void mvdr_kernel(
    const float* __restrict__ spec,    // (B,T,F,M,2)
    const float* __restrict__ corrS,   // (B,T,F,M,M,2)
    const float* __restrict__ corrN,   // (B,T,F,M,M,2)
    float* __restrict__ out)           // (B,F,T,2)
{
    __shared__ __align__(16) unsigned char ldsMat[MATB];
    __shared__ __align__(16) unsigned char ldsSpec[SPECB];

    const int tid  = threadIdx.x;
    const int wave = tid >> 6;
    const int lane = tid & 63;
    const size_t blockCell = (size_t)blockIdx.x * CELLS;

    // ---- phase 1: stage Phi_N + spec (coalesced, async to LDS) ----
    {
        const char* gN = (const char*)corrN + blockCell * 200;
        const size_t remN = (size_t)TOTAL * 200 - blockCell * 200;
        for (int c = wave; c < MATB / 1024; c += 2) {
            size_t off = (size_t)c * 1024 + (size_t)lane * 16;
            if (off + 16 <= remN)
                load_lds16(gN + off, (char*)ldsMat + off);
        }
        const char* gX = (const char*)spec + blockCell * 40;
        const size_t remX = (size_t)TOTAL * 40 - blockCell * 40;
        for (int c = wave; c < SPECB / 1024; c += 2) {
            size_t off = (size_t)c * 1024 + (size_t)lane * 16;
            if (off + 16 <= remX)
                load_lds16(gX + off, (char*)ldsSpec + off);
        }
    }
    __syncthreads();   // drains vmcnt before barrier

    // ---- read Phi_N into registers ----
    float Ar[MD][MD], Ai[MD][MD];
    {
        const float2* lm = (const float2*)ldsMat;
#pragma unroll
        for (int i = 0; i < MD; ++i)
#pragma unroll
            for (int j = 0; j < MD; ++j) {
                float2 v = lm[tid * (MD * MD) + i * MD + j];
                Ar[i][j] = v.x; Ai[i][j] = v.y;
            }
    }
    __syncthreads();   // everyone done reading N; buffer free for S

    // ---- issue Phi_S staging (async; overlaps the inversion below) ----
    {
        const char* gS = (const char*)corrS + blockCell * 200;
        const size_t remS = (size_t)TOTAL * 200 - blockCell * 200;
        for (int c = wave; c < MATB / 1024; c += 2) {
            size_t off = (size_t)c * 1024 + (size_t)lane * 16;
            if (off + 16 <= remS)
                load_lds16(gS + off, (char*)ldsMat + off);
        }
    }

    // ---- invert Phi_N in registers (Gauss-Jordan, partial pivoting) ----
#pragma unroll
    for (int i = 0; i < MD; ++i) { Ar[i][i] += 1e-7f; Ai[i][i] += 1e-7f; }

    bool sw[MD][MD];
#pragma unroll
    for (int k = 0; k < MD; ++k) {
#pragma unroll
        for (int j = k + 1; j < MD; ++j) {
            bool s = (Ar[j][k] * Ar[j][k] + Ai[j][k] * Ai[j][k]) >
                     (Ar[k][k] * Ar[k][k] + Ai[k][k] * Ai[k][k]);
            sw[k][j] = s;
#pragma unroll
            for (int c = 0; c < MD; ++c) {
                float ta, tb;
                ta = Ar[k][c]; tb = Ar[j][c];
                Ar[k][c] = s ? tb : ta; Ar[j][c] = s ? ta : tb;
                ta = Ai[k][c]; tb = Ai[j][c];
                Ai[k][c] = s ? tb : ta; Ai[j][c] = s ? ta : tb;
            }
        }
        float pr = Ar[k][k], pi = Ai[k][k];
        float invd = 1.0f / (pr * pr + pi * pi);
        float ipr = pr * invd, ipi = -pi * invd;   // 1/pivot
        Ar[k][k] = ipr; Ai[k][k] = ipi;
#pragma unroll
        for (int c = 0; c < MD; ++c) {
            if (c == k) continue;
            float xr = Ar[k][c], xi = Ai[k][c];
            Ar[k][c] = xr * ipr - xi * ipi;
            Ai[k][c] = xr * ipi + xi * ipr;
        }
#pragma unroll
        for (int i2 = 0; i2 < MD; ++i2) {
            if (i2 == k) continue;
            float fr = Ar[i2][k], fi = Ai[i2][k];
#pragma unroll
            for (int c = 0; c < MD; ++c) {
                if (c == k) continue;
                float xr = Ar[k][c], xi = Ai[k][c];
                Ar[i2][c] -= fr * xr - fi * xi;
                Ai[i2][c] -= fr * xi + fi * xr;
            }
            Ar[i2][k] = -(fr * ipr - fi * ipi);
            Ai[i2][k] = -(fr * ipi + fi * ipr);
        }
    }
    // reverse-order column fixup for row interchanges
#pragma unroll
    for (int k = MD - 1; k >= 0; --k) {
#pragma unroll
        for (int j = MD - 1; j > k; --j) {
            bool s = sw[k][j];
#pragma unroll
            for (int r = 0; r < MD; ++r) {
                float ta, tb;
                ta = Ar[r][k]; tb = Ar[r][j];
                Ar[r][k] = s ? tb : ta; Ar[r][j] = s ? ta : tb;
                ta = Ai[r][k]; tb = Ai[r][j];
                Ai[r][k] = s ? tb : ta; Ai[r][j] = s ? ta : tb;
            }
        }
    }

    __syncthreads();   // S staged (vmcnt drained) and visible

    // ---- stream Phi_S from LDS: trace(N^-1 S), a1 = N^-1 S[:,0] ----
    float trr = 0.f, tri = 0.f;
    float a1r[MD] = {0.f, 0.f, 0.f, 0.f, 0.f};
    float a1i[MD] = {0.f, 0.f, 0.f, 0.f, 0.f};
    {
        const float2* lm = (const float2*)ldsMat;
#pragma unroll
        for (int j = 0; j < MD; ++j) {
#pragma unroll
            for (int i = 0; i < MD; ++i) {
                float2 sv = lm[tid * (MD * MD) + j * MD + i];
                // trace += inv[i][j] * S[j][i]
                trr += Ar[i][j] * sv.x - Ai[i][j] * sv.y;
                tri += Ar[i][j] * sv.y + Ai[i][j] * sv.x;
                if (i == 0) {
#pragma unroll
                    for (int m = 0; m < MD; ++m) {
                        a1r[m] += Ar[m][j] * sv.x - Ai[m][j] * sv.y;
                        a1i[m] += Ar[m][j] * sv.y + Ai[m][j] * sv.x;
                    }
                }
            }
        }
    }
    const float eps = 1.1920929e-07f;
    trr += eps; tri += eps;

    // ---- z = sum_m conj(a1[m]) * x[m] (spec from LDS) ----
    float zr = 0.f, zi = 0.f;
    {
        const float2* lx = (const float2*)ldsSpec;
#pragma unroll
        for (int m = 0; m < MD; ++m) {
            float2 x = lx[tid * MD + m];
            zr += a1r[m] * x.x + a1i[m] * x.y;
            zi += a1r[m] * x.y - a1i[m] * x.x;
        }
    }

    // S_hat = z * (trr + i*tri) / |tr|^2
    float inv2 = 1.0f / (trr * trr + tri * tri);
    float shr = (zr * trr - zi * tri) * inv2;
    float shi = (zr * tri + zi * trr) * inv2;

    // ---- store (B,F,T,2) ----
    size_t idx = blockCell + tid;
    if (idx < (size_t)TOTAL) {
        int f  = (int)(idx % FF);
        int bt = (int)(idx / FF);
        int t  = bt % TT;
        int b  = bt / TT;
        float2* po = reinterpret_cast<float2*>(out);
        po[((size_t)b * FF + f) * TT + t] = make_float2(shr, shi);
    }
}

extern "C" void kernel_launch(void* const* d_in, const int* in_sizes, int n_in,
                              void* d_out, int out_size, void* d_ws, size_t ws_size,
                              hipStream_t stream) {
    const float* spec  = (const float*)d_in[0];
    const float* corrS = (const float*)d_in[1];
    const float* corrN = (const float*)d_in[2];
    float* out = (float*)d_out;

    int blocks = (TOTAL + CELLS - 1) / CELLS;
    mvdr_kernel<<<blocks, CELLS, 0, stream>>>(spec, corrS, corrN, out);
}